// Round 7
// baseline (3370.873 us; speedup 1.0000x reference)
//
#include <hip/hip_runtime.h>

// Liquid NN: BATCH=64, SEQ=256, IN=512, HID=1024, 2 layers, tau=0.5.
// h0(t) = h0 + a0*2*(tanh(x_t@W0^T + b0 + h0@U0^T) - h0)
// h1(t) = h1 + a1*2*(tanh(h0(t)@W1^T + b1 + h1@U1^T) - h1)
// Output: h1(255) as f32 (64,1024).
//
// R11: R9/R10 falsified the sync-fabric theory (barriers/polls/invs worth
// <1us/step total). Period == role1's straight-line body (~11us = 26k cyc);
// accounting leaves ~18k cyc of EXPOSED L2 LATENCY inside gemm_slab: the
// 1-block-deep prefetch gives each 8x-b128 load batch only 32 MFMA (~620cyc)
// of cover vs contended-L2 latency (64 waves on one 128KB ring slot, ~1us).
// FIX: role1's two independent slabs (W1*h0(t), U1*h1(t-1)) are FUSED into an
// interleaved dual-slab GEMM (gemm_dual): per mt-block, the next A-batches of
// BOTH streams are in flight under 64 MFMA (~1240cyc) of cover. Shared acc
// (the two products sum anyway) keeps acc at 64 VGPR. Est ~490 VGPR: OK at
// 1 wave/SIMD (512 budget, m08/m69); REVERT TRIGGER: VGPR_Count=512/spill.
// Role0 (1-slab body ~3us < role1's) is NOT the critical cycle: untouched.
//
// Kept from R10/R9/R6 (all verified): counter sync substrate (cnt0/cnt1 words,
// per-wave full-condition polls, no consumer barriers), no l1_inv (capacity
// argument held: absmax unchanged), NT wx loads, fast exp tanh, XOR-swizzled
// LDS reduce, k_wx @2048 blocks, 1 WG/CU (R8 lesson: no occupancy cap).
// Protocol (depth-8 rings, unchanged):
//   role0 s: cnt0[s-1]==16, cnt1[s-8]==16; role1 t: cnt0[t]==16, cnt1[t-1]==16
//   publish: tid0 fetch_add AFTER __syncthreads (vmcnt0 drain of h stores).

typedef _Float16 f16;
typedef _Float16 f16x8 __attribute__((ext_vector_type(8)));
typedef float    f32x4 __attribute__((ext_vector_type(4)));

#define B_  64
#define S_  256
#define IN_ 512
#define H_  1024

static constexpr size_t OFF_WX  = 0;         // S*B*H f16 = 33554432
static constexpr size_t OFF_H0R = 33554432;  // 8*B*H f16 = 1048576
static constexpr size_t OFF_H1R = 34603008;  // 8*B*H f16 = 1048576
static constexpr size_t OFF_FLG = 35651584;  // sync area (memset 8192 B)
// flg ints: cnt0[257]@0, cnt1[257]@512, ecnt[8]@1024, chosen@1032, ticket@1033

#define AGENT __HIP_MEMORY_SCOPE_AGENT

// ---------------- kernel: Wx = x @ W0^T + b0 (f32 in, f16 out) ----------------
__global__ __launch_bounds__(256) void k_wx(const float* __restrict__ x,
                                            const float* __restrict__ W0,
                                            const float* __restrict__ b0,
                                            f16* __restrict__ wx) {
  __shared__ uint4 xs[4096];  // 64 rows x 64 8-half chunks, chunk' = kc ^ (row&7)
  const int tid = threadIdx.x;
  const int w = tid >> 6, lane = tid & 63;
  const int q = lane >> 4, l15 = lane & 15;
  const int cslice = blockIdx.x & 15;
  const int rblock = blockIdx.x >> 4;  // 0..127
  const int c = cslice * 64 + w * 16 + l15;

  f16x8 Bf[16];  // B[k][n] = W0[c][k], lane holds k = kf*32 + q*8 + j
#pragma unroll
  for (int kf = 0; kf < 16; ++kf) {
    const float* p = W0 + (size_t)c * IN_ + kf * 32 + q * 8;
    f16x8 v;
#pragma unroll
    for (int j = 0; j < 8; ++j) v[j] = (f16)p[j];
    Bf[kf] = v;
  }
  const float bias = b0[c];

  for (int rt = 0; rt < 2; ++rt) {
    const int row0 = rblock * 128 + rt * 64;
    __syncthreads();
#pragma unroll
    for (int it = 0; it < 16; ++it) {
      int g = it * 256 + tid;
      int r = g >> 6, kc = g & 63;
      const float* xp = x + (size_t)(row0 + r) * IN_ + kc * 8;
      float4 v0 = *(const float4*)xp;
      float4 v1 = *(const float4*)(xp + 4);
      f16x8 h;
      h[0] = (f16)v0.x; h[1] = (f16)v0.y; h[2] = (f16)v0.z; h[3] = (f16)v0.w;
      h[4] = (f16)v1.x; h[5] = (f16)v1.y; h[6] = (f16)v1.z; h[7] = (f16)v1.w;
      xs[r * 64 + (kc ^ (r & 7))] = *(uint4*)&h;
    }
    __syncthreads();
    f32x4 acc[4] = {};
#pragma unroll
    for (int mt = 0; mt < 4; ++mt) {
      const int r = mt * 16 + l15;
#pragma unroll
      for (int kf = 0; kf < 16; ++kf) {
        uint4 av = xs[r * 64 + ((kf * 4 + q) ^ (r & 7))];
        f16x8 a = *(f16x8*)&av;
        acc[mt] = __builtin_amdgcn_mfma_f32_16x16x32_f16(a, Bf[kf], acc[mt], 0, 0, 0);
      }
    }
#pragma unroll
    for (int mt = 0; mt < 4; ++mt) {
#pragma unroll
      for (int r = 0; r < 4; ++r) {
        int rowg = row0 + mt * 16 + q * 4 + r;  // = b*256 + t
        int b = rowg >> 8, t = rowg & 255;
        wx[((size_t)t * B_ + b) * H_ + c] = (f16)(acc[mt][r] + bias);
      }
    }
  }
}

// ---------------- persistent recurrent kernel ----------------
// counter poll, per-wave: lane 0 waits cnt[idx] >= 16. ONE word, ONE tx per
// check, s_sleep(4) backoff after the first (hot) check. idx<0 -> no-op.
__device__ __forceinline__ void pollc(const int* cn, int idx, int lane) {
  if (idx < 0) return;
  const int* p = cn + idx;
  bool pend = (lane == 0);
  if (pend && __hip_atomic_load((int*)p, __ATOMIC_RELAXED, AGENT) >= 16)
    pend = false;
  while (__ballot(pend)) {
    __builtin_amdgcn_s_sleep(4);
    if (pend && __hip_atomic_load((int*)p, __ATOMIC_RELAXED, AGENT) >= 16)
      pend = false;
  }
}

// dual poll, per-wave: lane 0 waits a[ia]>=16, lane 1 waits b[ib]>=16.
__device__ __forceinline__ void pollc2(const int* a, int ia,
                                       const int* b, int ib, int lane) {
  const bool la = (lane == 0) && (ia >= 0);
  const bool lb = (lane == 1) && (ib >= 0);
  const int* p = la ? (a + ia) : (b + (ib < 0 ? 0 : ib));
  bool pend = la || lb;
  if (pend && __hip_atomic_load((int*)p, __ATOMIC_RELAXED, AGENT) >= 16)
    pend = false;
  while (__ballot(pend)) {
    __builtin_amdgcn_s_sleep(4);
    if (pend && __hip_atomic_load((int*)p, __ATOMIC_RELAXED, AGENT) >= 16)
      pend = false;
  }
}

// fast tanh: t = e^{-2|x|} in (0,1], tanh = sign(x)*(1-t)/(1+t). ~1e-7 abs err.
__device__ __forceinline__ float fast_tanh(float x) {
  float t = __expf(-2.0f * fabsf(x));
  float r = (1.0f - t) / (1.0f + t);
  return copysignf(r, x);
}

// one wave: 64-batch x 64-col x 256-K slab, software-pipelined A loads.
__device__ __forceinline__ void gemm_slab(const f16* __restrict__ A, int kbase,
                                          int l15, int q,
                                          const f16x8 (&Bf)[4][8], f32x4 (&acc)[4][4]) {
  f16x8 cur[8], nxt[8];
  const f16* ar0 = A + (size_t)l15 * H_ + kbase + q * 8;
#pragma unroll
  for (int kf = 0; kf < 8; ++kf) cur[kf] = *(const f16x8*)(ar0 + kf * 32);
#pragma unroll
  for (int mt = 0; mt < 4; ++mt) {
    if (mt < 3) {
      const f16* ar = A + (size_t)((mt + 1) * 16 + l15) * H_ + kbase + q * 8;
#pragma unroll
      for (int kf = 0; kf < 8; ++kf) nxt[kf] = *(const f16x8*)(ar + kf * 32);
    }
#pragma unroll
    for (int nt = 0; nt < 4; ++nt)
#pragma unroll
      for (int kf = 0; kf < 8; ++kf)
        acc[mt][nt] = __builtin_amdgcn_mfma_f32_16x16x32_f16(cur[kf], Bf[nt][kf],
                                                             acc[mt][nt], 0, 0, 0);
#pragma unroll
    for (int kf = 0; kf < 8; ++kf) cur[kf] = nxt[kf];
  }
}

// fused dual-slab: two independent A streams (A0,A1) x two B sets into ONE
// shared acc. Per mt-block, both next A-batches are in flight under 64 MFMA
// (~1240cyc) of cover -> contended-L2 latency hidden (the R11 fix).
__device__ __forceinline__ void gemm_dual(const f16* __restrict__ A0,
                                          const f16* __restrict__ A1, int kbase,
                                          int l15, int q,
                                          const f16x8 (&Bf0)[4][8],
                                          const f16x8 (&Bf1)[4][8],
                                          f32x4 (&acc)[4][4]) {
  f16x8 curA[8], curB[8], nxtA[8], nxtB[8];
  const f16* a0 = A0 + (size_t)l15 * H_ + kbase + q * 8;
  const f16* a1 = A1 + (size_t)l15 * H_ + kbase + q * 8;
#pragma unroll
  for (int kf = 0; kf < 8; ++kf) curA[kf] = *(const f16x8*)(a0 + kf * 32);
#pragma unroll
  for (int kf = 0; kf < 8; ++kf) curB[kf] = *(const f16x8*)(a1 + kf * 32);
#pragma unroll
  for (int mt = 0; mt < 4; ++mt) {
    if (mt < 3) {
      const f16* p0 = A0 + (size_t)((mt + 1) * 16 + l15) * H_ + kbase + q * 8;
#pragma unroll
      for (int kf = 0; kf < 8; ++kf) nxtA[kf] = *(const f16x8*)(p0 + kf * 32);
    }
#pragma unroll
    for (int nt = 0; nt < 4; ++nt)
#pragma unroll
      for (int kf = 0; kf < 8; ++kf)
        acc[mt][nt] = __builtin_amdgcn_mfma_f32_16x16x32_f16(curA[kf], Bf0[nt][kf],
                                                             acc[mt][nt], 0, 0, 0);
    if (mt < 3) {
      const f16* p1 = A1 + (size_t)((mt + 1) * 16 + l15) * H_ + kbase + q * 8;
#pragma unroll
      for (int kf = 0; kf < 8; ++kf) nxtB[kf] = *(const f16x8*)(p1 + kf * 32);
    }
#pragma unroll
    for (int nt = 0; nt < 4; ++nt)
#pragma unroll
      for (int kf = 0; kf < 8; ++kf)
        acc[mt][nt] = __builtin_amdgcn_mfma_f32_16x16x32_f16(curB[kf], Bf1[nt][kf],
                                                             acc[mt][nt], 0, 0, 0);
#pragma unroll
    for (int kf = 0; kf < 8; ++kf) { curA[kf] = nxtA[kf]; curB[kf] = nxtB[kf]; }
  }
}

__global__ __launch_bounds__(256, 1) void k_persist(
    const float* __restrict__ U0, const float* __restrict__ W1,
    const float* __restrict__ U1, const float* __restrict__ alpha0,
    const float* __restrict__ alpha1, const float* __restrict__ b1,
    const f16* __restrict__ wx, f16* h0r, f16* h1r, int* flg, float* out) {
  // red[ks][i][col]: D[m][n] of K-slice ks, m=(i>>4)*16+(col>>4)*4+(i&3),
  // n=((i>>2)&3)*16+(col&15), stored XOR-swizzled at col' = col ^ ((i&3)<<2).
  // aligned(16): epilogue does b128 LDS reads (under-aligned b128 = fault).
  __shared__ __attribute__((aligned(16))) float red[4][64][64];  // exactly 64 KiB
  const int tid = threadIdx.x;
  const int w = tid >> 6, lane = tid & 63;
  const int q = lane >> 4, l15 = lane & 15;

  int* cnt0   = flg;         // cnt0[s] = #role0 WGs that finished step s
  int* cnt1   = flg + 512;   // cnt1[t] = #role1 WGs that finished step t
  int* ecnt   = flg + 1024;
  int* chosen = flg + 1032;
  int* ticket = flg + 1033;

  // ---- elect one XCD; 32 workers there; everyone else exits (R4-validated) ----
  const int xcc = (int)__builtin_amdgcn_s_getreg(6164) & 7;  // HW_REG_XCC_ID
  int* sh = (int*)&red[0][0][0];
  if (tid == 0) {
    __hip_atomic_fetch_add(ecnt + xcc, 1, __ATOMIC_RELAXED, AGENT);
    if (blockIdx.x == 0) {
      int sel = -1;
      while (sel < 0) {
        for (int i = 0; i < 8; ++i)
          if (__hip_atomic_load(ecnt + i, __ATOMIC_RELAXED, AGENT) >= 32) { sel = i; break; }
        if (sel < 0) __builtin_amdgcn_s_sleep(1);
      }
      __hip_atomic_fetch_add(chosen, sel + 1, __ATOMIC_RELAXED, AGENT);
    }
    int ch;
    while ((ch = __hip_atomic_load(chosen, __ATOMIC_RELAXED, AGENT)) == 0)
      __builtin_amdgcn_s_sleep(1);
    int my = -1;
    if (xcc == ch - 1) my = __hip_atomic_fetch_add(ticket, 1, __ATOMIC_RELAXED, AGENT);
    sh[0] = my;
  }
  __syncthreads();
  const int myid = sh[0];
  __syncthreads();
  if (myid < 0 || myid >= 32) return;
  const int role = myid >> 4, slice = myid & 15;
  const int c0 = slice * 64;
  const int kbase = w * 256;

  // ---- weight slices into registers: B[k][n] = Wm[c][k] ----
  f16x8 BfA[4][8];  // role0: U0 ; role1: W1
  f16x8 BfB[4][8];  // role1: U1
  {
    const float* WmA = (role == 0) ? U0 : W1;
#pragma unroll
    for (int nt = 0; nt < 4; ++nt)
#pragma unroll
      for (int kf = 0; kf < 8; ++kf) {
        const float* p = WmA + (size_t)(c0 + nt * 16 + l15) * H_ + kbase + kf * 32 + q * 8;
        f16x8 v;
#pragma unroll
        for (int j = 0; j < 8; ++j) v[j] = (f16)p[j];
        BfA[nt][kf] = v;
      }
    if (role == 1) {
#pragma unroll
      for (int nt = 0; nt < 4; ++nt)
#pragma unroll
        for (int kf = 0; kf < 8; ++kf) {
          const float* p = U1 + (size_t)(c0 + nt * 16 + l15) * H_ + kbase + kf * 32 + q * 8;
          f16x8 v;
#pragma unroll
          for (int j = 0; j < 8; ++j) v[j] = (f16)p[j];
          BfB[nt][kf] = v;
        }
    }
  }

  // ---- epilogue ownership: thread owns batch row bown, cols cbase..cbase+15 ----
  const int bown = w * 16 + (lane & 15);
  const int gq   = lane >> 4;
  const int iidx = w * 16 + gq * 4 + (lane & 3);  // fixed LDS row
  const int lsb  = ((lane >> 2) & 3) * 16;        // fixed logical col base
  const int swz  = (lane & 3) << 2;               // read-side XOR (row&3 == lane&3)
  const int cbase = c0 + gq * 16;

  f16x8 cfh[2], bsh[2];  // packed alpha*2 and bias for the 16 owned cols
  {
    const float* ap = ((role == 0) ? alpha0 : alpha1) + cbase;
    const float* bp = b1 + cbase;
    f16x8 t0, t1, u0, u1;
#pragma unroll
    for (int j = 0; j < 8; ++j) {
      t0[j] = (f16)(ap[j] * 2.0f);
      t1[j] = (f16)(ap[8 + j] * 2.0f);
      u0[j] = (f16)bp[j];
      u1[j] = (f16)bp[8 + j];
    }
    cfh[0] = t0; cfh[1] = t1; bsh[0] = u0; bsh[1] = u1;
  }

  float hst[16];
#pragma unroll
  for (int i = 0; i < 16; ++i) hst[i] = 0.f;

  if (role == 0) {
    for (int s = 0; s < 256; ++s) {
      // prefetch wx[s] for owned (b, cols): 2 x b128 NT loads (no L2 allocate ->
      // h-rings stay L2-resident), in flight during the poll
      const f16* wp = wx + ((size_t)s * B_ + bown) * H_ + cbase;
      f16x8 wxa = __builtin_nontemporal_load((const f16x8*)wp);
      f16x8 wxb = __builtin_nontemporal_load((const f16x8*)(wp + 8));
      f32x4 acc[4][4] = {};
      if (s > 0) {
        // every wave checks BOTH full conditions itself -> no barrier needed.
        pollc2(cnt0, s - 1, cnt1, s - 8, lane);
        gemm_slab(h0r + (size_t)((s - 1) & 7) * B_ * H_, kbase, l15, q, BfA, acc);
      }
#pragma unroll
      for (int mt = 0; mt < 4; ++mt)
#pragma unroll
        for (int nt = 0; nt < 4; ++nt)
#pragma unroll
          for (int r = 0; r < 4; ++r)
            red[w][mt * 16 + nt * 4 + r][lane ^ (r << 2)] = acc[mt][nt][r];
      __syncthreads();
      float vs[16];
#pragma unroll
      for (int ks = 0; ks < 4; ++ks)
#pragma unroll
        for (int ch = 0; ch < 4; ++ch) {
          f32x4 v = *(const f32x4*)&red[ks][iidx][lsb + ((ch << 2) ^ swz)];
          if (ks == 0) {
            vs[ch*4+0] = v[0]; vs[ch*4+1] = v[1]; vs[ch*4+2] = v[2]; vs[ch*4+3] = v[3];
          } else {
            vs[ch*4+0] += v[0]; vs[ch*4+1] += v[1]; vs[ch*4+2] += v[2]; vs[ch*4+3] += v[3];
          }
        }
      f16* hw = h0r + (size_t)(s & 7) * B_ * H_ + (size_t)bown * H_ + cbase;
      f16x8 o0, o1;
#pragma unroll
      for (int j = 0; j < 16; ++j) {
        float wxv = (float)((j < 8) ? wxa[j] : wxb[j - 8]);
        float cf  = (float)((j < 8) ? cfh[0][j] : cfh[1][j - 8]);
        float th = fast_tanh(vs[j] + wxv);
        float h = hst[j];
        h = h + cf * (th - h);
        hst[j] = h;
        if (j < 8) o0[j] = (f16)h; else o1[j - 8] = (f16)h;
      }
      *(f16x8*)hw = o0;
      *(f16x8*)(hw + 8) = o1;
      // drain barrier: all waves' h stores at L2 before publish; ALSO fences
      // red reuse (all reduce-reads of this step precede it).
      __syncthreads();
      if (tid == 0)
        __hip_atomic_fetch_add(cnt0 + s, 1, __ATOMIC_RELAXED, AGENT);
    }
  } else {
    for (int t = 0; t < 256; ++t) {
      f32x4 acc[4][4] = {};
      // both deps up front (per-wave, no barrier): cnt0[t] is ~8 steps early
      // (ring slack) -> instant; cnt1[t-1] lands ~when this WG published t-1.
      pollc2(cnt0, t, cnt1, t - 1, lane);
      if (t > 0) {
        gemm_dual(h0r + (size_t)(t & 7) * B_ * H_,
                  h1r + (size_t)((t - 1) & 7) * B_ * H_,
                  kbase, l15, q, BfA, BfB, acc);
      } else {
        gemm_slab(h0r + (size_t)(t & 7) * B_ * H_, kbase, l15, q, BfA, acc);
      }
#pragma unroll
      for (int mt = 0; mt < 4; ++mt)
#pragma unroll
        for (int nt = 0; nt < 4; ++nt)
#pragma unroll
          for (int r = 0; r < 4; ++r)
            red[w][mt * 16 + nt * 4 + r][lane ^ (r << 2)] = acc[mt][nt][r];
      __syncthreads();
      float vs[16];
#pragma unroll
      for (int ks = 0; ks < 4; ++ks)
#pragma unroll
        for (int ch = 0; ch < 4; ++ch) {
          f32x4 v = *(const f32x4*)&red[ks][iidx][lsb + ((ch << 2) ^ swz)];
          if (ks == 0) {
            vs[ch*4+0] = v[0]; vs[ch*4+1] = v[1]; vs[ch*4+2] = v[2]; vs[ch*4+3] = v[3];
          } else {
            vs[ch*4+0] += v[0]; vs[ch*4+1] += v[1]; vs[ch*4+2] += v[2]; vs[ch*4+3] += v[3];
          }
        }
      f16* hw = h1r + (size_t)(t & 7) * B_ * H_ + (size_t)bown * H_ + cbase;
      f16x8 o0, o1;
#pragma unroll
      for (int j = 0; j < 16; ++j) {
        float bs = (float)((j < 8) ? bsh[0][j] : bsh[1][j - 8]);
        float cf = (float)((j < 8) ? cfh[0][j] : cfh[1][j - 8]);
        float th = fast_tanh(vs[j] + bs);
        float h = hst[j];
        h = h + cf * (th - h);
        hst[j] = h;
        if (j < 8) o0[j] = (f16)h; else o1[j - 8] = (f16)h;
      }
      *(f16x8*)hw = o0;
      *(f16x8*)(hw + 8) = o1;
      if (t == 255) {
        float* op = out + (size_t)bown * H_ + cbase;
#pragma unroll
        for (int ch = 0; ch < 4; ++ch) {
          float4 vv;
          vv.x = hst[ch*4+0]; vv.y = hst[ch*4+1]; vv.z = hst[ch*4+2]; vv.w = hst[ch*4+3];
          *(float4*)(op + ch * 4) = vv;
        }
      }
      __syncthreads();  // drain h1 stores + fence red reuse
      if (tid == 0)
        __hip_atomic_fetch_add(cnt1 + t, 1, __ATOMIC_RELAXED, AGENT);
    }
  }
}

// Swizzle identity: writer lane L stores logical col L at physical col
// L ^ ((i&3)<<2). Reader (row iidx, iidx&3 == lane&3) reads physical
// lsb + ((ch<<2) ^ ((lane&3)<<2)) + nn, which un-XORs to logical
// lsb + ch*4 + nn. Writes are lane-permutations (conflict-free); b128 reads
// spread across all 32 banks (conflict-free).

extern "C" void kernel_launch(void* const* d_in, const int* in_sizes, int n_in,
                              void* d_out, int out_size, void* d_ws, size_t ws_size,
                              hipStream_t stream) {
  const float* x  = (const float*)d_in[0];
  const float* W0 = (const float*)d_in[1];
  const float* U0 = (const float*)d_in[2];
  const float* b0 = (const float*)d_in[3];
  const float* a0 = (const float*)d_in[4];
  const float* W1 = (const float*)d_in[5];
  const float* U1 = (const float*)d_in[6];
  const float* b1 = (const float*)d_in[7];
  const float* a1 = (const float*)d_in[8];
  char* ws = (char*)d_ws;
  f16*   wx  = (f16*)(ws + OFF_WX);
  f16*   h0r = (f16*)(ws + OFF_H0R);
  f16*   h1r = (f16*)(ws + OFF_H1R);
  int*   flg = (int*)(ws + OFF_FLG);
  float* out = (float*)d_out;

  hipMemsetAsync(flg, 0, 8192, stream);            // counters/election start at 0
  k_wx<<<2048, 256, 0, stream>>>(x, W0, b0, wx);   // parallel Wx GEMM (more TLP)

  // 256 blocks: every XCD gets >=32 by pigeonhole; workers self-select onto one.
  k_persist<<<256, 256, 0, stream>>>(U0, W1, U1, a0, a1, b1, wx, h0r, h1r, flg, out);
}

// Round 9
// 1199.448 us; speedup vs baseline: 2.8104x; 2.8104x over previous
//
#include <hip/hip_runtime.h>

// Liquid NN: BATCH=64, SEQ=256, IN=512, HID=1024, 2 layers, tau=0.5.
// h0(t) = h0 + a0*2*(tanh(x_t@W0^T + b0 + h0@U0^T) - h0)
// h1(t) = h1 + a1*2*(tanh(h0(t)@W1^T + b1 + h1@U1^T) - h1)
// Output: h1(255) as f32 (64,1024).
//
// R13 = R12 (batch-split pipelines) with the VALIDATED 256-block grid.
// R12's 512-block launch was the only untested element in a round that died
// with a container failure (likely election hang under 2x/XCD oversubscription
// with xgrp-waiters holding slots). 256 blocks = exactly 32/XCD by pigeonhole
// (the R4/R10-validated residency), so every XCD reaches its 32-ticket
// threshold from resident blocks alone; block 0 claims the first 4.
//
// Design (R12 theory, unchanged): the ~10.5us step of the 32-WG single-XCD
// design is the latency-exposed 64-row slab body at 1 wave/SIMD (R4-R11:
// sync fabric <1us; deeper per-wave ILP spills). Batch rows are INDEPENDENT
// -> split B=64 into 4 groups of 16 rows, 4 self-contained pipelines on 4
// XCDs (128 worker WGs). Per wave per slab: ONE 8x-b128 load batch (all in
// flight at once, no multi-batch latency exposure) + 32 MFMA; acc 64->16.
// Groups never touch: own rings+counters in their own XCD L2; wx read-only,
// row-partitioned. Numerics per row IDENTICAL to R10 (same K-split/order).
//
// Election: every block tickets on its XCD (ecnt); block 0 assigns groups
// 0..3 to the first 4 XCDs reaching 32 tickets, -1 to the rest. Tickets
// 0..31 on a claimed XCD are its workers (role=ticket>>4, slice=ticket&15).
// Per-group protocol (counters, depth-8 rings, targets 16 - R10-validated):
//   role0 s: cnt0[s-1]==16, cnt1[s-8]==16 (ring); publish cnt0[s] after drain
//   role1 t: cnt0[t]==16 (h0(t) ready), cnt1[t-1]==16; publish cnt1[t]
//   per-wave full-condition polls (no consumer barriers); no l1_inv (R10:
//   capacity-eviction argument held, absmax unchanged).
// R6 keepers: NT wx loads, fast exp tanh, XOR-swizzled LDS reduce (16-row
// map re-derived below), k_wx @2048 blocks.

typedef _Float16 f16;
typedef _Float16 f16x4 __attribute__((ext_vector_type(4)));
typedef _Float16 f16x8 __attribute__((ext_vector_type(8)));
typedef float    f32x4 __attribute__((ext_vector_type(4)));

#define B_  64
#define S_  256
#define IN_ 512
#define H_  1024
#define GR_ 16   // batch rows per group

static constexpr size_t OFF_WX  = 0;         // S*B*H f16 = 33554432
static constexpr size_t OFF_H0R = 33554432;  // 4 groups x 8*16*H f16 = 1048576
static constexpr size_t OFF_H1R = 34603008;  // 4 groups x 8*16*H f16 = 1048576
static constexpr size_t OFF_FLG = 35651584;  // sync area (memset 32768 B)
// flg ints: group g: cnt0 @ g*1024, cnt1 @ g*1024+512 (g=0..3)
//           election: ecnt[8] @ 4096, xgrp[8] @ 4104

#define AGENT __HIP_MEMORY_SCOPE_AGENT

// ---------------- kernel: Wx = x @ W0^T + b0 (f32 in, f16 out) ----------------
__global__ __launch_bounds__(256) void k_wx(const float* __restrict__ x,
                                            const float* __restrict__ W0,
                                            const float* __restrict__ b0,
                                            f16* __restrict__ wx) {
  __shared__ uint4 xs[4096];  // 64 rows x 64 8-half chunks, chunk' = kc ^ (row&7)
  const int tid = threadIdx.x;
  const int w = tid >> 6, lane = tid & 63;
  const int q = lane >> 4, l15 = lane & 15;
  const int cslice = blockIdx.x & 15;
  const int rblock = blockIdx.x >> 4;  // 0..127
  const int c = cslice * 64 + w * 16 + l15;

  f16x8 Bf[16];  // B[k][n] = W0[c][k], lane holds k = kf*32 + q*8 + j
#pragma unroll
  for (int kf = 0; kf < 16; ++kf) {
    const float* p = W0 + (size_t)c * IN_ + kf * 32 + q * 8;
    f16x8 v;
#pragma unroll
    for (int j = 0; j < 8; ++j) v[j] = (f16)p[j];
    Bf[kf] = v;
  }
  const float bias = b0[c];

  for (int rt = 0; rt < 2; ++rt) {
    const int row0 = rblock * 128 + rt * 64;
    __syncthreads();
#pragma unroll
    for (int it = 0; it < 16; ++it) {
      int g = it * 256 + tid;
      int r = g >> 6, kc = g & 63;
      const float* xp = x + (size_t)(row0 + r) * IN_ + kc * 8;
      float4 v0 = *(const float4*)xp;
      float4 v1 = *(const float4*)(xp + 4);
      f16x8 h;
      h[0] = (f16)v0.x; h[1] = (f16)v0.y; h[2] = (f16)v0.z; h[3] = (f16)v0.w;
      h[4] = (f16)v1.x; h[5] = (f16)v1.y; h[6] = (f16)v1.z; h[7] = (f16)v1.w;
      xs[r * 64 + (kc ^ (r & 7))] = *(uint4*)&h;
    }
    __syncthreads();
    f32x4 acc[4] = {};
#pragma unroll
    for (int mt = 0; mt < 4; ++mt) {
      const int r = mt * 16 + l15;
#pragma unroll
      for (int kf = 0; kf < 16; ++kf) {
        uint4 av = xs[r * 64 + ((kf * 4 + q) ^ (r & 7))];
        f16x8 a = *(f16x8*)&av;
        acc[mt] = __builtin_amdgcn_mfma_f32_16x16x32_f16(a, Bf[kf], acc[mt], 0, 0, 0);
      }
    }
#pragma unroll
    for (int mt = 0; mt < 4; ++mt) {
#pragma unroll
      for (int r = 0; r < 4; ++r) {
        int rowg = row0 + mt * 16 + q * 4 + r;  // = b*256 + t
        int b = rowg >> 8, t = rowg & 255;
        wx[((size_t)t * B_ + b) * H_ + c] = (f16)(acc[mt][r] + bias);
      }
    }
  }
}

// ---------------- persistent recurrent kernel ----------------
// counter poll, per-wave: lane 0 waits cnt[idx] >= 16 (16 producer WGs/role).
__device__ __forceinline__ void pollc(const int* cn, int idx, int lane) {
  if (idx < 0) return;
  const int* p = cn + idx;
  bool pend = (lane == 0);
  if (pend && __hip_atomic_load((int*)p, __ATOMIC_RELAXED, AGENT) >= 16)
    pend = false;
  while (__ballot(pend)) {
    __builtin_amdgcn_s_sleep(4);
    if (pend && __hip_atomic_load((int*)p, __ATOMIC_RELAXED, AGENT) >= 16)
      pend = false;
  }
}

// dual poll, per-wave: lane 0 waits a[ia]>=16, lane 1 waits b[ib]>=16.
__device__ __forceinline__ void pollc2(const int* a, int ia,
                                       const int* b, int ib, int lane) {
  const bool la = (lane == 0) && (ia >= 0);
  const bool lb = (lane == 1) && (ib >= 0);
  const int* p = la ? (a + ia) : (b + (ib < 0 ? 0 : ib));
  bool pend = la || lb;
  if (pend && __hip_atomic_load((int*)p, __ATOMIC_RELAXED, AGENT) >= 16)
    pend = false;
  while (__ballot(pend)) {
    __builtin_amdgcn_s_sleep(4);
    if (pend && __hip_atomic_load((int*)p, __ATOMIC_RELAXED, AGENT) >= 16)
      pend = false;
  }
}

// fast tanh: t = e^{-2|x|} in (0,1], tanh = sign(x)*(1-t)/(1+t). ~1e-7 abs err.
__device__ __forceinline__ float fast_tanh(float x) {
  float t = __expf(-2.0f * fabsf(x));
  float r = (1.0f - t) / (1.0f + t);
  return copysignf(r, x);
}

// 16-row slab: M=16 (one MFMA m-tile), 64 cols, K=256 per wave. ONE batch of
// 8 b128 loads (all in flight immediately) + 32 MFMA.
__device__ __forceinline__ void slab16(const f16* __restrict__ A, int kbase,
                                       int l15, int q,
                                       const f16x8 (&Bf)[4][8], f32x4 (&acc)[4]) {
  f16x8 cur[8];
  const f16* ar = A + (size_t)l15 * H_ + kbase + q * 8;
#pragma unroll
  for (int kf = 0; kf < 8; ++kf) cur[kf] = *(const f16x8*)(ar + kf * 32);
#pragma unroll
  for (int nt = 0; nt < 4; ++nt)
#pragma unroll
    for (int kf = 0; kf < 8; ++kf)
      acc[nt] = __builtin_amdgcn_mfma_f32_16x16x32_f16(cur[kf], Bf[nt][kf],
                                                       acc[nt], 0, 0, 0);
}

__global__ __launch_bounds__(256, 1) void k_persist(
    const float* __restrict__ U0, const float* __restrict__ W1,
    const float* __restrict__ U1, const float* __restrict__ alpha0,
    const float* __restrict__ alpha1, const float* __restrict__ b1,
    const f16* __restrict__ wx, f16* h0r, f16* h1r, int* flg, float* out) {
  // red[ks][i][col]: wave ks's D (16x64). i = nt*4 + r, col' = lane ^ (r<<2)
  // (m = q*4+r, n = nt*16+l15, lane = q*16+l15). 16 KiB.
  __shared__ __attribute__((aligned(16))) float red[4][16][64];
  const int tid = threadIdx.x;
  const int w = tid >> 6, lane = tid & 63;
  const int q = lane >> 4, l15 = lane & 15;

  int* ecnt = flg + 4096;  // per-XCD arrival tickets
  int* xgrp = flg + 4104;  // per-XCD group assignment: 0=pending, g+1, or -1

  // ---- election: 4 XCDs x 32 workers. 256 blocks = exactly 32/XCD resident
  // (validated residency), so every XCD reaches threshold from resident
  // blocks alone; block 0 claims the first 4 and marks the rest -1.
  const int xcc = (int)__builtin_amdgcn_s_getreg(6164) & 7;  // HW_REG_XCC_ID
  int* sh = (int*)&red[0][0][0];
  if (tid == 0) {
    int my = __hip_atomic_fetch_add(ecnt + xcc, 1, __ATOMIC_RELAXED, AGENT);
    if (blockIdx.x == 0) {
      unsigned taken = 0; int assigned = 0;
      while (assigned < 4) {
        for (int i = 0; i < 8 && assigned < 4; ++i)
          if (!((taken >> i) & 1) &&
              __hip_atomic_load(ecnt + i, __ATOMIC_RELAXED, AGENT) >= 32) {
            taken |= 1u << i;
            __hip_atomic_store(xgrp + i, assigned + 1, __ATOMIC_RELAXED, AGENT);
            ++assigned;
          }
        if (assigned < 4) __builtin_amdgcn_s_sleep(1);
      }
      for (int i = 0; i < 8; ++i)
        if (!((taken >> i) & 1))
          __hip_atomic_store(xgrp + i, -1, __ATOMIC_RELAXED, AGENT);
    }
    int grp = -1;
    if (my < 32) {
      int v;
      while ((v = __hip_atomic_load(xgrp + xcc, __ATOMIC_RELAXED, AGENT)) == 0)
        __builtin_amdgcn_s_sleep(1);
      if (v > 0) grp = v - 1;
    }
    sh[0] = (grp >= 0) ? my : -1;
    sh[1] = grp;
  }
  __syncthreads();
  const int myid = sh[0], g = sh[1];
  __syncthreads();
  if (myid < 0) return;
  const int role = myid >> 4, slice = myid & 15;
  const int c0 = slice * 64;
  const int kbase = w * 256;

  int* cnt0 = flg + g * 1024;        // cnt0[s] = #role0 WGs finished step s
  int* cnt1 = flg + g * 1024 + 512;  // cnt1[t] = #role1 WGs finished step t
  f16* h0g = h0r + (size_t)g * 8 * GR_ * H_;  // group's depth-8 rings
  f16* h1g = h1r + (size_t)g * 8 * GR_ * H_;

  // ---- weight slices into registers: B[k][n] = Wm[c][k] ----
  f16x8 BfA[4][8];  // role0: U0 ; role1: W1
  f16x8 BfB[4][8];  // role1: U1
  {
    const float* WmA = (role == 0) ? U0 : W1;
#pragma unroll
    for (int nt = 0; nt < 4; ++nt)
#pragma unroll
      for (int kf = 0; kf < 8; ++kf) {
        const float* p = WmA + (size_t)(c0 + nt * 16 + l15) * H_ + kbase + kf * 32 + q * 8;
        f16x8 v;
#pragma unroll
        for (int j = 0; j < 8; ++j) v[j] = (f16)p[j];
        BfA[nt][kf] = v;
      }
    if (role == 1) {
#pragma unroll
      for (int nt = 0; nt < 4; ++nt)
#pragma unroll
        for (int kf = 0; kf < 8; ++kf) {
          const float* p = U1 + (size_t)(c0 + nt * 16 + l15) * H_ + kbase + kf * 32 + q * 8;
          f16x8 v;
#pragma unroll
          for (int j = 0; j < 8; ++j) v[j] = (f16)p[j];
          BfB[nt][kf] = v;
        }
    }
  }

  // ---- epilogue ownership: thread owns (row16, 4 cols) — coalesced stores.
  const int row16 = tid >> 4, cgrp = tid & 15;
  const int iidx  = (cgrp >> 2) * 4 + (row16 & 3);
  const int bcol  = (row16 >> 2) * 16 + ((((cgrp & 3) * 4)) ^ ((row16 & 3) << 2));
  const int coff  = c0 + cgrp * 4;   // global col base of the 4 owned cols
  const int bglob = g * GR_ + row16; // global batch row

  float cf[4], bs[4];
  {
    const float* ap = ((role == 0) ? alpha0 : alpha1) + coff;
    const float* bp = b1 + coff;
#pragma unroll
    for (int j = 0; j < 4; ++j) { cf[j] = ap[j] * 2.0f; bs[j] = bp[j]; }
  }

  float hst[4] = {0.f, 0.f, 0.f, 0.f};

  if (role == 0) {
    for (int s = 0; s < 256; ++s) {
      // NT wx prefetch (8 B/thread, coalesced), in flight during the poll.
      const f16* wp = wx + ((size_t)s * B_ + bglob) * H_ + coff;
      f16x4 wxv = __builtin_nontemporal_load((const f16x4*)wp);
      f32x4 acc[4] = {};
      if (s > 0) {
        pollc2(cnt0, s - 1, cnt1, s - 8, lane);  // peers s-1 + ring slot free
        slab16(h0g + (size_t)((s - 1) & 7) * GR_ * H_, kbase, l15, q, BfA, acc);
      }
#pragma unroll
      for (int nt = 0; nt < 4; ++nt)
#pragma unroll
        for (int r = 0; r < 4; ++r)
          red[w][nt * 4 + r][lane ^ (r << 2)] = acc[nt][r];
      __syncthreads();
      f32x4 vs = {};
#pragma unroll
      for (int ks = 0; ks < 4; ++ks) {
        f32x4 v = *(const f32x4*)&red[ks][iidx][bcol];
        vs[0] += v[0]; vs[1] += v[1]; vs[2] += v[2]; vs[3] += v[3];
      }
      f16* hw = h0g + (size_t)(s & 7) * GR_ * H_ + (size_t)row16 * H_ + coff;
      f16x4 o;
#pragma unroll
      for (int j = 0; j < 4; ++j) {
        float th = fast_tanh(vs[j] + (float)wxv[j]);
        float h = hst[j];
        h = h + cf[j] * (th - h);
        hst[j] = h;
        o[j] = (f16)h;
      }
      *(f16x4*)hw = o;
      __syncthreads();  // drain h stores to L2 + fence red reuse
      if (tid == 0)
        __hip_atomic_fetch_add(cnt0 + s, 1, __ATOMIC_RELAXED, AGENT);
    }
  } else {
    for (int t = 0; t < 256; ++t) {
      pollc2(cnt0, t, cnt1, t - 1, lane);  // h0(t) ready (8-early) + peers t-1
      f32x4 acc[4] = {};
      // both A batches issued up front (16 b128 in flight), then MFMAs.
      f16x8 cA[8], cB[8];
      const f16* a0 = h0g + (size_t)(t & 7) * GR_ * H_ + (size_t)l15 * H_ + kbase + q * 8;
#pragma unroll
      for (int kf = 0; kf < 8; ++kf) cA[kf] = *(const f16x8*)(a0 + kf * 32);
      if (t > 0) {
        const f16* a1 = h1g + (size_t)((t - 1) & 7) * GR_ * H_ + (size_t)l15 * H_ + kbase + q * 8;
#pragma unroll
        for (int kf = 0; kf < 8; ++kf) cB[kf] = *(const f16x8*)(a1 + kf * 32);
      }
#pragma unroll
      for (int nt = 0; nt < 4; ++nt)
#pragma unroll
        for (int kf = 0; kf < 8; ++kf)
          acc[nt] = __builtin_amdgcn_mfma_f32_16x16x32_f16(cA[kf], BfA[nt][kf],
                                                           acc[nt], 0, 0, 0);
      if (t > 0) {
#pragma unroll
        for (int nt = 0; nt < 4; ++nt)
#pragma unroll
          for (int kf = 0; kf < 8; ++kf)
            acc[nt] = __builtin_amdgcn_mfma_f32_16x16x32_f16(cB[kf], BfB[nt][kf],
                                                             acc[nt], 0, 0, 0);
      }
#pragma unroll
      for (int nt = 0; nt < 4; ++nt)
#pragma unroll
        for (int r = 0; r < 4; ++r)
          red[w][nt * 4 + r][lane ^ (r << 2)] = acc[nt][r];
      __syncthreads();
      f32x4 vs = {};
#pragma unroll
      for (int ks = 0; ks < 4; ++ks) {
        f32x4 v = *(const f32x4*)&red[ks][iidx][bcol];
        vs[0] += v[0]; vs[1] += v[1]; vs[2] += v[2]; vs[3] += v[3];
      }
      f16* hw = h1g + (size_t)(t & 7) * GR_ * H_ + (size_t)row16 * H_ + coff;
      f16x4 o;
#pragma unroll
      for (int j = 0; j < 4; ++j) {
        float th = fast_tanh(vs[j] + bs[j]);
        float h = hst[j];
        h = h + cf[j] * (th - h);
        hst[j] = h;
        o[j] = (f16)h;
      }
      *(f16x4*)hw = o;
      if (t == 255) {
        float* op = out + (size_t)bglob * H_ + coff;
        float4 vv;
        vv.x = hst[0]; vv.y = hst[1]; vv.z = hst[2]; vv.w = hst[3];
        *(float4*)op = vv;
      }
      __syncthreads();  // drain h1 stores + fence red reuse
      if (tid == 0)
        __hip_atomic_fetch_add(cnt1 + t, 1, __ATOMIC_RELAXED, AGENT);
    }
  }
}

// LDS map identity (16-row variant): writer wave ks, lane = q*16+l15 stores
// D[m][n] (m=q*4+r, n=nt*16+l15) at red[ks][nt*4+r][(q*16+l15)^(r<<2)].
// Reader (row16,cgrp) wants (m=row16, n=cgrp*4+j): r=row16&3, nt=cgrp>>2,
// q=row16>>2, l15=(cgrp&3)*4+j -> i=nt*4+r, col'=q*16+(((cgrp&3)*4+j)^(r<<2)).
// XOR touches bits 2-3 only, j lives in bits 0-1 -> col' = bcol + j: one
// aligned f32x4 read. (row16,cgrp)->(i,bcol) is bijective over 256 threads.

extern "C" void kernel_launch(void* const* d_in, const int* in_sizes, int n_in,
                              void* d_out, int out_size, void* d_ws, size_t ws_size,
                              hipStream_t stream) {
  const float* x  = (const float*)d_in[0];
  const float* W0 = (const float*)d_in[1];
  const float* U0 = (const float*)d_in[2];
  const float* b0 = (const float*)d_in[3];
  const float* a0 = (const float*)d_in[4];
  const float* W1 = (const float*)d_in[5];
  const float* U1 = (const float*)d_in[6];
  const float* b1 = (const float*)d_in[7];
  const float* a1 = (const float*)d_in[8];
  char* ws = (char*)d_ws;
  f16*   wx  = (f16*)(ws + OFF_WX);
  f16*   h0r = (f16*)(ws + OFF_H0R);
  f16*   h1r = (f16*)(ws + OFF_H1R);
  int*   flg = (int*)(ws + OFF_FLG);
  float* out = (float*)d_out;

  hipMemsetAsync(flg, 0, 32768, stream);           // counters/election start at 0
  k_wx<<<2048, 256, 0, stream>>>(x, W0, b0, wx);   // parallel Wx GEMM

  // 256 blocks: exactly 32 resident per XCD (validated); first 4 XCDs to fill
  // claim groups 0-3; all other blocks exit.
  k_persist<<<256, 256, 0, stream>>>(U0, W1, U1, a0, a1, b1, wx, h0r, h1r, flg, out);
}